// Round 10
// baseline (169.318 us; speedup 1.0000x reference)
//
#include <hip/hip_runtime.h>
#include <hip/hip_bf16.h>

#define S_LEN  2048
#define HDIM   1024
#define NHEADS 16
#define HEADD  64
#define BATCH  2
#define MTOT   (BATCH * S_LEN)          // 4096
#define K2EXP  0.04508422f              // log2(e)/32 (folded into Wq/bq)

typedef __attribute__((ext_vector_type(8)))  __bf16 bf16x8;
typedef __attribute__((ext_vector_type(4)))  __bf16 bf16x4;
typedef __attribute__((ext_vector_type(4)))  float  f32x4;
typedef __attribute__((ext_vector_type(16))) float  f32x16;

__device__ __forceinline__ void gload16(const void* g, void* l) {
  __builtin_amdgcn_global_load_lds(
      (const __attribute__((address_space(1))) void*)g,
      (__attribute__((address_space(3))) void*)l, 16, 0, 0);
}
// swizzled LDS read; STRIDE = row stride in bytes, 16B-slot XOR swizzle
template<int STRIDE>
__device__ __forceinline__ bf16x8 lds_rdS(const __bf16* base, int row, int bcol) {
  const char* p = (const char*)base + row * STRIDE + (bcol ^ ((row & (STRIDE / 16 - 1)) << 4));
  return *(const bf16x8*)p;
}
__device__ __forceinline__ unsigned cvtpk_bf16(float lo, float hi) {
  unsigned r;
  asm("v_cvt_pk_bf16_f32 %0, %1, %2" : "=v"(r) : "v"(lo), "v"(hi));
  return r;
}
__device__ __forceinline__ void plswap(unsigned& a, unsigned& b) {
  asm volatile("v_permlane32_swap_b32 %0, %1" : "+v"(a), "+v"(b));
}

// ========================================================= fused prologue ===
// blocks [0,6144): f32->bf16 cvt of q/k/v
// blocks [6144,38912): mask -> hi-specific permuted 16-bit tables
//   mbH[hi][b][seg 32][q 2048] u32; lo16 bit j = mask[q][seg*64+(j&3)+8*(j>>2)+4*hi],
//   hi16 bit j = same +32. (1 MB total, L2-resident)
// blocks [38912,39936): W[k][n] f32 -> Wt[n][k] bf16 (Wq scaled by K2EXP)
__global__ __launch_bounds__(256)
void prologue_kernel(const float* __restrict__ q, const float* __restrict__ k,
                     const float* __restrict__ v, const int* __restrict__ mask,
                     const float* __restrict__ Wq, const float* __restrict__ Wk,
                     const float* __restrict__ Wv, const float* __restrict__ Wfc,
                     __bf16* __restrict__ Qc, __bf16* __restrict__ Kc,
                     __bf16* __restrict__ Vc, unsigned* __restrict__ mbH,
                     __bf16* __restrict__ Wt)
{
  __shared__ float T[64][65];
  const int id = blockIdx.x;
  const int tid = threadIdx.x;
  if (id < 6144) {
    const int z = id >> 11, blk = id & 2047;
    const float* src = (z == 0) ? q : (z == 1) ? k : v;
    __bf16* dst = (z == 0) ? Qc : (z == 1) ? Kc : Vc;
    const size_t i = ((size_t)blk * 256 + tid) * 8;
    const float4 a = *(const float4*)&src[i];
    const float4 c = *(const float4*)&src[i + 4];
    bf16x8 o;
    o[0] = (__bf16)a.x; o[1] = (__bf16)a.y; o[2] = (__bf16)a.z; o[3] = (__bf16)a.w;
    o[4] = (__bf16)c.x; o[5] = (__bf16)c.y; o[6] = (__bf16)c.z; o[7] = (__bf16)c.w;
    *(bf16x8*)&dst[i] = o;
  } else if (id < 38912) {
    const size_t idx = (size_t)(id - 6144) * 256 + tid;
    const int m = mask[idx];
    const unsigned long long bal = __ballot(m != 0);
    const int lane = tid & 63;
    if ((lane & 31) == 0) {
      const int hh = lane >> 5;
      unsigned wlo = 0, whi = 0;
      #pragma unroll
      for (int j = 0; j < 16; ++j) {
        const int kvl = (j & 3) + 8 * (j >> 2) + 4 * hh;
        wlo |= (unsigned)((bal >> kvl) & 1ULL) << j;
        whi |= (unsigned)((bal >> (32 + kvl)) & 1ULL) << j;
      }
      const int b   = (int)(idx >> 22);
      const int qq  = (int)(idx >> 11) & 2047;
      const int seg = ((int)idx & 2047) >> 6;
      mbH[(((size_t)(hh * 2 + b)) * 32 + seg) * S_LEN + qq] = wlo | (whi << 16);
    }
  } else {
    const int f = id - 38912;
    const int z = f >> 8;
    const float* W = (z == 0) ? Wq : (z == 1) ? Wk : (z == 2) ? Wv : Wfc;
    const float sc = (z == 0) ? K2EXP : 1.0f;
    __bf16* O = Wt + (size_t)z * HDIM * HDIM;
    const int k0 = ((f >> 4) & 15) * 64, n0 = (f & 15) * 64;
    const int r  = tid >> 4;
    const int c4 = (tid & 15) * 4;
    #pragma unroll
    for (int p = 0; p < 4; ++p) {
      const int row = r + p * 16;
      const float4 vv = *(const float4*)&W[(size_t)(k0 + row) * HDIM + n0 + c4];
      T[row][c4 + 0] = vv.x; T[row][c4 + 1] = vv.y;
      T[row][c4 + 2] = vv.z; T[row][c4 + 3] = vv.w;
    }
    __syncthreads();
    #pragma unroll
    for (int p = 0; p < 4; ++p) {
      const int n = r + p * 16;
      bf16x4 o;
      #pragma unroll
      for (int i = 0; i < 4; ++i) o[i] = (__bf16)(T[c4 + i][n] * sc);
      *(bf16x4*)&O[(size_t)(n0 + n) * HDIM + k0 + c4] = o;
    }
  }
}

// ================================================================== GEMM ===
// BMT x 128 tile, BK=64, dbuf, global_load_lds, XCD-swizzled block mapping.
// MODE 0: out bf16 (+bias*bscale). MODE 1: out f32 (+bias+resid).
// MODE 2: out = V^T per head (bf16) for attention.
template<int MODE, int BMT>
__device__ __forceinline__ void gemm_body(
    __bf16* As, __bf16* Bs,   // As: [2][BMT][64], Bs: [2][128][64] (flat)
    const __bf16* __restrict__ A, const __bf16* __restrict__ Wt,
    const float* __restrict__ bias, float bscale,
    const float* __restrict__ resid,
    __bf16* __restrict__ Ob, float* __restrict__ Of, __bf16* __restrict__ Vtg)
{
  constexpr int AI = BMT / 32;          // wave M-tiles (4 or 2)
  const int tid = threadIdx.x, lane = tid & 63, w = tid >> 6;
  const int fr = lane & 15, k8 = (lane >> 4) * 8;
  const int wr = w >> 1, wc = w & 1;
  // XCD-aware swizzle (nwg % 8 == 0 -> bijective)
  const int f   = blockIdx.x + gridDim.x * blockIdx.y;
  const int cpx = (gridDim.x * gridDim.y) >> 3;
  const int fs  = (f & 7) * cpx + (f >> 3);
  const int m0 = (fs / gridDim.x) * BMT, n0 = (fs % gridDim.x) * 128;
  const int srow8 = lane >> 3, slot = lane & 7;

  f32x4 acc[AI][4] = {};

  #define G_STAGE(kt, bf)                                                    \
    {                                                                        \
      _Pragma("unroll")                                                      \
      for (int c = 0; c < AI; ++c) {                                         \
        const int ra = w * (BMT / 4) + c * 8 + srow8;                        \
        gload16(&A[(size_t)(m0 + ra) * HDIM + (kt) * 64 + ((slot ^ (ra & 7)) * 8)], \
                (void*)&As[((bf) * BMT + ra) * 64]);                         \
      }                                                                      \
      _Pragma("unroll")                                                      \
      for (int c = 0; c < 4; ++c) {                                          \
        const int rb = w * 32 + c * 8 + srow8;                               \
        gload16(&Wt[(size_t)(n0 + rb) * HDIM + (kt) * 64 + ((slot ^ (rb & 7)) * 8)], \
                (void*)&Bs[((bf) * 128 + rb) * 64]);                         \
      }                                                                      \
    }

  #define G_COMPUTE(bf)                                                      \
    {                                                                        \
      _Pragma("unroll")                                                      \
      for (int kk = 0; kk < 64; kk += 32) {                                  \
        bf16x8 a[AI], b[4];                                                  \
        _Pragma("unroll")                                                    \
        for (int i = 0; i < AI; ++i)                                         \
          a[i] = lds_rdS<128>(&As[(bf) * BMT * 64], wr * (BMT / 2) + i * 16 + fr, (kk + k8) * 2); \
        _Pragma("unroll")                                                    \
        for (int j = 0; j < 4; ++j)                                          \
          b[j] = lds_rdS<128>(&Bs[(bf) * 128 * 64], wc * 64 + j * 16 + fr, (kk + k8) * 2); \
        _Pragma("unroll")                                                    \
        for (int i = 0; i < AI; ++i)                                         \
          _Pragma("unroll")                                                  \
          for (int j = 0; j < 4; ++j)                                        \
            acc[i][j] = __builtin_amdgcn_mfma_f32_16x16x32_bf16(a[i], b[j], acc[i][j], 0, 0, 0); \
      }                                                                      \
    }

  G_STAGE(0, 0)
  for (int kt = 0; kt < 15; ++kt) {
    G_STAGE(kt + 1, (kt + 1) & 1)
    if constexpr (BMT == 128) asm volatile("s_waitcnt vmcnt(8)" ::: "memory");
    else                      asm volatile("s_waitcnt vmcnt(6)" ::: "memory");
    __builtin_amdgcn_s_barrier();
    __builtin_amdgcn_sched_barrier(0);
    __builtin_amdgcn_s_setprio(1);
    G_COMPUTE(kt & 1)
    __builtin_amdgcn_s_setprio(0);
    __builtin_amdgcn_sched_barrier(0);
    __builtin_amdgcn_s_barrier();
  }
  asm volatile("s_waitcnt vmcnt(0)" ::: "memory");
  __builtin_amdgcn_s_barrier();
  G_COMPUTE(1)

  const int rg = (lane >> 4) * 4;
  #pragma unroll
  for (int i = 0; i < AI; ++i) {
    #pragma unroll
    for (int j = 0; j < 4; ++j) {
      const int col = n0 + wc * 64 + j * 16 + fr;
      if constexpr (MODE == 2) {
        const int h = col >> 6, hd = col & 63;
        const int row = m0 + wr * (BMT / 2) + i * 16 + rg;
        const int bq = row >> 11, qq = row & 2047;
        bf16x4 o;
        #pragma unroll
        for (int r = 0; r < 4; ++r) o[r] = (__bf16)(acc[i][j][r] + bias[col]);
        *(bf16x4*)&Vtg[(((size_t)bq * NHEADS + h) * HEADD + hd) * S_LEN + qq] = o;
      } else {
        #pragma unroll
        for (int r = 0; r < 4; ++r) {
          const int row = m0 + wr * (BMT / 2) + i * 16 + rg + r;
          if constexpr (MODE == 0) {
            Ob[(size_t)row * HDIM + col] = (__bf16)(acc[i][j][r] + bias[col] * bscale);
          } else {
            Of[(size_t)row * HDIM + col] =
                acc[i][j][r] + bias[col] + resid[(size_t)row * HDIM + col];
          }
        }
      }
    }
  }
  #undef G_STAGE
  #undef G_COMPUTE
}

__global__ __launch_bounds__(256)
void qkv_kernel(const __bf16* __restrict__ Qc, const __bf16* __restrict__ Kc,
                const __bf16* __restrict__ Vc, const __bf16* __restrict__ Wt,
                const float* __restrict__ bq, const float* __restrict__ bk,
                const float* __restrict__ bv,
                __bf16* __restrict__ Qb, __bf16* __restrict__ Kb,
                __bf16* __restrict__ Vtg)
{
  __shared__ __bf16 smem[2 * 128 * 64 * 2];
  __bf16* As = smem;
  __bf16* Bs = smem + 2 * 128 * 64;
  const int z = blockIdx.z;
  if (z == 2) {
    gemm_body<2, 128>(As, Bs, Vc, Wt + (size_t)2 * HDIM * HDIM, bv, 1.0f,
                      nullptr, nullptr, nullptr, Vtg);
  } else {
    gemm_body<0, 128>(As, Bs, z ? Kc : Qc, Wt + (size_t)z * HDIM * HDIM,
                      z ? bk : bq, z ? 1.0f : K2EXP, nullptr,
                      z ? Kb : Qb, nullptr, nullptr);
  }
}

__global__ __launch_bounds__(256)
void fc_kernel(const __bf16* __restrict__ A, const __bf16* __restrict__ Wt,
               const float* __restrict__ bias, const float* __restrict__ resid,
               float* __restrict__ Of)
{
  __shared__ __bf16 smem[2 * 64 * 64 + 2 * 128 * 64];
  __bf16* As = smem;
  __bf16* Bs = smem + 2 * 64 * 64;
  gemm_body<1, 64>(As, Bs, A, Wt + (size_t)3 * HDIM * HDIM, bias, 1.0f, resid,
                   nullptr, Of, nullptr);
}

// ============================================================= attention ===
// 4 waves, 64 q/block; wave (qt,kvh)=(w>>1,w&1) computes the 32q x 32kv-half
// slice of each 64-kv tile -> grid (32 bh x 32 q) = 1024 blocks = 4/CU =
// 16 waves/CU in 4 independent sync domains (2x resident parallelism vs r9).
// kv-half partials combined at the end through retired K/V LDS.
// SINGLE barrier per tile (ledger: barrier(t) => compute(t-1) reads of
// buf^1 retired => stage(t+1)->buf^1 safe); counted vmcnt(5).
// Swapped QK^T: lane owns q = lane&31; kv = (reg&3)+8*(reg>>2)+4*(lane>>5)
// + 32*kvh. Q pre-scaled by log2(e)/32 -> exp2 direct. Mask mbH + sbfe.
// Row-sum via ones-B MFMA in PV accumulator layout.
__global__ __launch_bounds__(256)
void attn_kernel(const __bf16* __restrict__ Qb, const __bf16* __restrict__ Kb,
                 const __bf16* __restrict__ Vtg, const unsigned* __restrict__ mbH,
                 __bf16* __restrict__ AO)
{
  __shared__ __align__(16) char smem[32768];
  __bf16 (*Ks)[64][64] = (__bf16(*)[64][64])smem;            // 16 KB
  __bf16 (*Vt)[64][64] = (__bf16(*)[64][64])(smem + 16384);  // 16 KB

  const int bh = blockIdx.x, b = bh >> 4, h = bh & 15;
  const int tid = threadIdx.x, lane = tid & 63, w = tid >> 6;
  const int fr = lane & 31, hi = lane >> 5;
  const int qt = w >> 1, kvh = w & 1;
  const int qw = blockIdx.y * 64 + qt * 32;
  const int q  = qw + fr;

  // Q B-frags (reused all tiles)
  bf16x8 qf[4];
  #pragma unroll
  for (int st = 0; st < 4; ++st)
    qf[st] = *(const bf16x8*)&Qb[((size_t)b * S_LEN + q) * HDIM + h * HEADD + st * 16 + hi * 8];

  // staging: wave w covers rows [w*16, w*16+16), two 8-row gloads per matrix
  const int srl = w * 16 + (lane >> 3);
  const int ssw = ((lane & 7) ^ (srl & 7)) * 8;
  const __bf16* ksrc = Kb  + ((size_t)b * S_LEN + srl) * HDIM + h * HEADD + ssw;
  const __bf16* vsrc = Vtg + ((size_t)bh * HEADD + srl) * S_LEN + ssw;
  const unsigned* tbl = mbH + ((size_t)(hi * 2 + b) * 32) * S_LEN + q;

  bf16x8 ones;
  #pragma unroll
  for (int e = 0; e < 8; ++e) ones[e] = (__bf16)1.0f;

  f32x16 o0 = {}, o1 = {}, l_acc = {};
  unsigned mv, nm = 0;

  // prologue: mask(0) + stage tile 0 -> buf0
  mv = tbl[0];
  gload16(ksrc,             (void*)&Ks[0][w * 16][0]);
  gload16(ksrc + 8 * HDIM,  (void*)&Ks[0][w * 16 + 8][0]);
  gload16(vsrc,             (void*)&Vt[0][w * 16][0]);
  gload16(vsrc + 8 * S_LEN, (void*)&Vt[0][w * 16 + 8][0]);

  for (int t = 0; t < 32; ++t) {
    const int buf = t & 1;
    __builtin_amdgcn_s_barrier();
    if (t < 31) {
      nm = tbl[(size_t)(t + 1) * S_LEN];
      const __bf16* kp = ksrc + (size_t)(t + 1) * 64 * HDIM;
      const __bf16* vp = vsrc + (size_t)(t + 1) * 64;
      gload16(kp,             (void*)&Ks[buf ^ 1][w * 16][0]);
      gload16(kp + 8 * HDIM,  (void*)&Ks[buf ^ 1][w * 16 + 8][0]);
      gload16(vp,             (void*)&Vt[buf ^ 1][w * 16][0]);
      gload16(vp + 8 * S_LEN, (void*)&Vt[buf ^ 1][w * 16 + 8][0]);
      asm volatile("s_waitcnt vmcnt(5)" ::: "memory");
    } else {
      asm volatile("s_waitcnt vmcnt(0)" ::: "memory");
    }
    __builtin_amdgcn_sched_barrier(0);

    const __bf16* Kbuf = &Ks[buf][0][0];
    const __bf16* Vbuf = &Vt[buf][0][0];

    // ---- S^T = K Q^T (this wave's 32-kv half)
    f32x16 s = {};
    __builtin_amdgcn_s_setprio(1);
    #pragma unroll
    for (int st = 0; st < 4; ++st)
      s = __builtin_amdgcn_mfma_f32_32x32x16_bf16(
          lds_rdS<128>(Kbuf, kvh * 32 + fr, st * 32 + hi * 16), qf[st], s, 0, 0, 0);
    __builtin_amdgcn_s_setprio(0);

    // ---- p = exp2(s) (scale pre-folded), mask via sbfe sign-bit AND
    float pp[16];
    #pragma unroll
    for (int j = 0; j < 16; ++j) {
      const float e = __builtin_amdgcn_exp2f(s[j]);
      const unsigned a = (unsigned)__builtin_amdgcn_sbfe(mv, j + 16 * kvh, 1);
      pp[j] = __uint_as_float(a & __float_as_uint(e));
    }

    // ---- P -> PV A-frags (cvt_pk + permlane32_swap)
    bf16x8 pa[2];
    #pragma unroll
    for (int g = 0; g < 2; ++g) {
      const int o = g * 8;
      unsigned x  = cvtpk_bf16(pp[o + 0], pp[o + 1]);
      unsigned x2 = cvtpk_bf16(pp[o + 2], pp[o + 3]);
      unsigned y  = cvtpk_bf16(pp[o + 4], pp[o + 5]);
      unsigned y2 = cvtpk_bf16(pp[o + 6], pp[o + 7]);
      plswap(x, y);
      plswap(x2, y2);
      union { unsigned u[4]; bf16x8 v; } uu;
      uu.u[0] = x; uu.u[1] = x2; uu.u[2] = y; uu.u[3] = y2;
      pa[g] = uu.v;
    }

    // ---- O += P V ; l += P 1   (kv-half columns of V^T)
    __builtin_amdgcn_s_setprio(1);
    #pragma unroll
    for (int g = 0; g < 2; ++g) {
      const int bcol = kvh * 64 + g * 32 + hi * 16;
      l_acc = __builtin_amdgcn_mfma_f32_32x32x16_bf16(pa[g], ones, l_acc, 0, 0, 0);
      o0 = __builtin_amdgcn_mfma_f32_32x32x16_bf16(
          pa[g], lds_rdS<128>(Vbuf, fr,      bcol), o0, 0, 0, 0);
      o1 = __builtin_amdgcn_mfma_f32_32x32x16_bf16(
          pa[g], lds_rdS<128>(Vbuf, 32 + fr, bcol), o1, 0, 0, 0);
    }
    __builtin_amdgcn_s_setprio(0);

    mv = nm;
  }

  // ---- combine kv-half partials through retired K/V LDS, then store
  __builtin_amdgcn_s_barrier();
  float* sh = (float*)smem;
  if (kvh) {
    float* p = sh + ((size_t)qt * 64 + lane) * 48;
    #pragma unroll
    for (int j = 0; j < 16; ++j) { p[j] = o0[j]; p[16 + j] = o1[j]; p[32 + j] = l_acc[j]; }
  }
  __builtin_amdgcn_s_barrier();
  if (!kvh) {
    const float* p = sh + ((size_t)qt * 64 + lane) * 48;
    #pragma unroll
    for (int g = 0; g < 4; ++g) {
      #pragma unroll
      for (int r = 0; r < 4; ++r) {
        const int j = g * 4 + r;
        const float inv = __builtin_amdgcn_rcpf(l_acc[j] + p[32 + j]);
        const int qq = qw + g * 8 + hi * 4 + r;
        AO[((size_t)b * S_LEN + qq) * HDIM + h * HEADD + fr]      =
            (__bf16)((o0[j] + p[j]) * inv);
        AO[((size_t)b * S_LEN + qq) * HDIM + h * HEADD + 32 + fr] =
            (__bf16)((o1[j] + p[16 + j]) * inv);
      }
    }
  }
}

// ============================================================= layernorm ===
__global__ __launch_bounds__(256)
void ln_kernel(float* __restrict__ y, const float* __restrict__ gamma,
               const float* __restrict__ beta)
{
  __shared__ float red[8];
  const int tid = threadIdx.x;
  float* p = y + (size_t)blockIdx.x * HDIM;

  float4 vv = *(const float4*)&p[tid * 4];
  float s  = vv.x + vv.y + vv.z + vv.w;
  float ss = vv.x * vv.x + vv.y * vv.y + vv.z * vv.z + vv.w * vv.w;
  #pragma unroll
  for (int d = 1; d < 64; d <<= 1) {
    s  += __shfl_xor(s, d);
    ss += __shfl_xor(ss, d);
  }
  const int wid = tid >> 6;
  if ((tid & 63) == 0) { red[wid * 2] = s; red[wid * 2 + 1] = ss; }
  __syncthreads();
  s  = red[0] + red[2] + red[4] + red[6];
  ss = red[1] + red[3] + red[5] + red[7];
  const float mean = s * (1.0f / HDIM);
  const float var  = ss * (1.0f / HDIM) - mean * mean;
  const float inv  = rsqrtf(var + 1e-5f);

  const float4 g  = *(const float4*)&gamma[tid * 4];
  const float4 bt = *(const float4*)&beta[tid * 4];
  vv.x = (vv.x - mean) * inv * g.x + bt.x;
  vv.y = (vv.y - mean) * inv * g.y + bt.y;
  vv.z = (vv.z - mean) * inv * g.z + bt.z;
  vv.w = (vv.w - mean) * inv * g.w + bt.w;
  *(float4*)&p[tid * 4] = vv;
}

// ================================================================ launch ===
extern "C" void kernel_launch(void* const* d_in, const int* in_sizes, int n_in,
                              void* d_out, int out_size, void* d_ws, size_t ws_size,
                              hipStream_t stream) {
  const float* q     = (const float*)d_in[0];
  const float* k     = (const float*)d_in[1];
  const float* v     = (const float*)d_in[2];
  const int*   mask  = (const int*)  d_in[3];
  const float* Wq    = (const float*)d_in[4];
  const float* bq    = (const float*)d_in[5];
  const float* Wk    = (const float*)d_in[6];
  const float* bk    = (const float*)d_in[7];
  const float* Wv    = (const float*)d_in[8];
  const float* bv    = (const float*)d_in[9];
  const float* Wfc   = (const float*)d_in[10];
  const float* bfc   = (const float*)d_in[11];
  const float* gamma = (const float*)d_in[12];
  const float* beta  = (const float*)d_in[13];
  float* out = (float*)d_out;

  char* ws = (char*)d_ws;
  const size_t MB16 = (size_t)MTOT * HDIM * 2;     // 8.39 MB per bf16 matrix
  unsigned* mbH = (unsigned*)ws;                   // 1 MB
  __bf16* Wt  = (__bf16*)(ws + (1u << 20));        // 8 MB
  __bf16* Qc  = (__bf16*)(ws + (1u << 20) + 4 * (size_t)HDIM * HDIM * 2);
  __bf16* Kc  = (__bf16*)((char*)Qc + MB16);
  __bf16* Vc  = (__bf16*)((char*)Kc + MB16);
  __bf16* Qb  = (__bf16*)((char*)Vc + MB16);
  __bf16* Kb  = (__bf16*)((char*)Qb + MB16);
  __bf16* Vtg = (__bf16*)((char*)Kb + MB16);       // V^T written by qkv z=2
  __bf16* AO  = Kc;   // alias: Kc dead after qkv

  const dim3 blk(256);

  prologue_kernel<<<dim3(39936), blk, 0, stream>>>(
      q, k, v, mask, Wq, Wk, Wv, Wfc, Qc, Kc, Vc, mbH, Wt);

  qkv_kernel<<<dim3(HDIM / 128, MTOT / 128, 3), blk, 0, stream>>>(
      Qc, Kc, Vc, Wt, bq, bk, bv, Qb, Kb, Vtg);

  attn_kernel<<<dim3(BATCH * NHEADS, S_LEN / 64), blk, 0, stream>>>(
      Qb, Kb, Vtg, mbH, AO);

  fc_kernel<<<dim3(HDIM / 128, MTOT / 64), blk, 0, stream>>>(
      AO, Wt, bfc, q, out);

  ln_kernel<<<dim3(MTOT), blk, 0, stream>>>(out, gamma, beta);
}

// Round 11
// 154.751 us; speedup vs baseline: 1.0941x; 1.0941x over previous
//
#include <hip/hip_runtime.h>
#include <hip/hip_bf16.h>

#define S_LEN  2048
#define HDIM   1024
#define NHEADS 16
#define HEADD  64
#define BATCH  2
#define MTOT   (BATCH * S_LEN)          // 4096
#define K2EXP  0.04508422f              // log2(e)/32 (folded into Wq/bq)

typedef __attribute__((ext_vector_type(8)))  __bf16 bf16x8;
typedef __attribute__((ext_vector_type(4)))  __bf16 bf16x4;
typedef __attribute__((ext_vector_type(4)))  float  f32x4;
typedef __attribute__((ext_vector_type(16))) float  f32x16;

__device__ __forceinline__ void gload16(const void* g, void* l) {
  __builtin_amdgcn_global_load_lds(
      (const __attribute__((address_space(1))) void*)g,
      (__attribute__((address_space(3))) void*)l, 16, 0, 0);
}
// swizzled LDS read; STRIDE = row stride in bytes, 16B-slot XOR swizzle
template<int STRIDE>
__device__ __forceinline__ bf16x8 lds_rdS(const __bf16* base, int row, int bcol) {
  const char* p = (const char*)base + row * STRIDE + (bcol ^ ((row & (STRIDE / 16 - 1)) << 4));
  return *(const bf16x8*)p;
}
__device__ __forceinline__ unsigned cvtpk_bf16(float lo, float hi) {
  unsigned r;
  asm("v_cvt_pk_bf16_f32 %0, %1, %2" : "=v"(r) : "v"(lo), "v"(hi));
  return r;
}
__device__ __forceinline__ void plswap(unsigned& a, unsigned& b) {
  asm volatile("v_permlane32_swap_b32 %0, %1" : "+v"(a), "+v"(b));
}

// ========================================================= fused prologue ===
// blocks [0,6144): f32->bf16 cvt of q/k/v
// blocks [6144,38912): mask -> hi-specific permuted 16-bit tables
//   mbH[hi][b][seg 32][q 2048] u32; lo16 bit j = mask[q][seg*64+(j&3)+8*(j>>2)+4*hi],
//   hi16 bit j = same +32. (1 MB total, L2-resident)
// blocks [38912,39936): W[k][n] f32 -> Wt[n][k] bf16 (Wq scaled by K2EXP)
__global__ __launch_bounds__(256)
void prologue_kernel(const float* __restrict__ q, const float* __restrict__ k,
                     const float* __restrict__ v, const int* __restrict__ mask,
                     const float* __restrict__ Wq, const float* __restrict__ Wk,
                     const float* __restrict__ Wv, const float* __restrict__ Wfc,
                     __bf16* __restrict__ Qc, __bf16* __restrict__ Kc,
                     __bf16* __restrict__ Vc, unsigned* __restrict__ mbH,
                     __bf16* __restrict__ Wt)
{
  __shared__ float T[64][65];
  const int id = blockIdx.x;
  const int tid = threadIdx.x;
  if (id < 6144) {
    const int z = id >> 11, blk = id & 2047;
    const float* src = (z == 0) ? q : (z == 1) ? k : v;
    __bf16* dst = (z == 0) ? Qc : (z == 1) ? Kc : Vc;
    const size_t i = ((size_t)blk * 256 + tid) * 8;
    const float4 a = *(const float4*)&src[i];
    const float4 c = *(const float4*)&src[i + 4];
    bf16x8 o;
    o[0] = (__bf16)a.x; o[1] = (__bf16)a.y; o[2] = (__bf16)a.z; o[3] = (__bf16)a.w;
    o[4] = (__bf16)c.x; o[5] = (__bf16)c.y; o[6] = (__bf16)c.z; o[7] = (__bf16)c.w;
    *(bf16x8*)&dst[i] = o;
  } else if (id < 38912) {
    const size_t idx = (size_t)(id - 6144) * 256 + tid;
    const int m = mask[idx];
    const unsigned long long bal = __ballot(m != 0);
    const int lane = tid & 63;
    if ((lane & 31) == 0) {
      const int hh = lane >> 5;
      unsigned wlo = 0, whi = 0;
      #pragma unroll
      for (int j = 0; j < 16; ++j) {
        const int kvl = (j & 3) + 8 * (j >> 2) + 4 * hh;
        wlo |= (unsigned)((bal >> kvl) & 1ULL) << j;
        whi |= (unsigned)((bal >> (32 + kvl)) & 1ULL) << j;
      }
      const int b   = (int)(idx >> 22);
      const int qq  = (int)(idx >> 11) & 2047;
      const int seg = ((int)idx & 2047) >> 6;
      mbH[(((size_t)(hh * 2 + b)) * 32 + seg) * S_LEN + qq] = wlo | (whi << 16);
    }
  } else {
    const int f = id - 38912;
    const int z = f >> 8;
    const float* W = (z == 0) ? Wq : (z == 1) ? Wk : (z == 2) ? Wv : Wfc;
    const float sc = (z == 0) ? K2EXP : 1.0f;
    __bf16* O = Wt + (size_t)z * HDIM * HDIM;
    const int k0 = ((f >> 4) & 15) * 64, n0 = (f & 15) * 64;
    const int r  = tid >> 4;
    const int c4 = (tid & 15) * 4;
    #pragma unroll
    for (int p = 0; p < 4; ++p) {
      const int row = r + p * 16;
      const float4 vv = *(const float4*)&W[(size_t)(k0 + row) * HDIM + n0 + c4];
      T[row][c4 + 0] = vv.x; T[row][c4 + 1] = vv.y;
      T[row][c4 + 2] = vv.z; T[row][c4 + 3] = vv.w;
    }
    __syncthreads();
    #pragma unroll
    for (int p = 0; p < 4; ++p) {
      const int n = r + p * 16;
      bf16x4 o;
      #pragma unroll
      for (int i = 0; i < 4; ++i) o[i] = (__bf16)(T[c4 + i][n] * sc);
      *(bf16x4*)&O[(size_t)(n0 + n) * HDIM + k0 + c4] = o;
    }
  }
}

// ================================================================== GEMM ===
// BMT x 128 tile, BK=64, dbuf, global_load_lds, XCD-swizzled block mapping.
// MODE 0: out bf16 (+bias*bscale). MODE 1: out f32 (+bias+resid).
// MODE 2: out = V^T per head (bf16) for attention.
template<int MODE, int BMT>
__device__ __forceinline__ void gemm_body(
    __bf16* As, __bf16* Bs,   // As: [2][BMT][64], Bs: [2][128][64] (flat)
    const __bf16* __restrict__ A, const __bf16* __restrict__ Wt,
    const float* __restrict__ bias, float bscale,
    const float* __restrict__ resid,
    __bf16* __restrict__ Ob, float* __restrict__ Of, __bf16* __restrict__ Vtg)
{
  constexpr int AI = BMT / 32;          // wave M-tiles (4 or 2)
  const int tid = threadIdx.x, lane = tid & 63, w = tid >> 6;
  const int fr = lane & 15, k8 = (lane >> 4) * 8;
  const int wr = w >> 1, wc = w & 1;
  // XCD-aware swizzle (nwg % 8 == 0 -> bijective)
  const int f   = blockIdx.x + gridDim.x * blockIdx.y;
  const int cpx = (gridDim.x * gridDim.y) >> 3;
  const int fs  = (f & 7) * cpx + (f >> 3);
  const int m0 = (fs / gridDim.x) * BMT, n0 = (fs % gridDim.x) * 128;
  const int srow8 = lane >> 3, slot = lane & 7;

  f32x4 acc[AI][4] = {};

  #define G_STAGE(kt, bf)                                                    \
    {                                                                        \
      _Pragma("unroll")                                                      \
      for (int c = 0; c < AI; ++c) {                                         \
        const int ra = w * (BMT / 4) + c * 8 + srow8;                        \
        gload16(&A[(size_t)(m0 + ra) * HDIM + (kt) * 64 + ((slot ^ (ra & 7)) * 8)], \
                (void*)&As[((bf) * BMT + ra) * 64]);                         \
      }                                                                      \
      _Pragma("unroll")                                                      \
      for (int c = 0; c < 4; ++c) {                                          \
        const int rb = w * 32 + c * 8 + srow8;                               \
        gload16(&Wt[(size_t)(n0 + rb) * HDIM + (kt) * 64 + ((slot ^ (rb & 7)) * 8)], \
                (void*)&Bs[((bf) * 128 + rb) * 64]);                         \
      }                                                                      \
    }

  #define G_COMPUTE(bf)                                                      \
    {                                                                        \
      _Pragma("unroll")                                                      \
      for (int kk = 0; kk < 64; kk += 32) {                                  \
        bf16x8 a[AI], b[4];                                                  \
        _Pragma("unroll")                                                    \
        for (int i = 0; i < AI; ++i)                                         \
          a[i] = lds_rdS<128>(&As[(bf) * BMT * 64], wr * (BMT / 2) + i * 16 + fr, (kk + k8) * 2); \
        _Pragma("unroll")                                                    \
        for (int j = 0; j < 4; ++j)                                          \
          b[j] = lds_rdS<128>(&Bs[(bf) * 128 * 64], wc * 64 + j * 16 + fr, (kk + k8) * 2); \
        _Pragma("unroll")                                                    \
        for (int i = 0; i < AI; ++i)                                         \
          _Pragma("unroll")                                                  \
          for (int j = 0; j < 4; ++j)                                        \
            acc[i][j] = __builtin_amdgcn_mfma_f32_16x16x32_bf16(a[i], b[j], acc[i][j], 0, 0, 0); \
      }                                                                      \
    }

  G_STAGE(0, 0)
  for (int kt = 0; kt < 15; ++kt) {
    G_STAGE(kt + 1, (kt + 1) & 1)
    if constexpr (BMT == 128) asm volatile("s_waitcnt vmcnt(8)" ::: "memory");
    else                      asm volatile("s_waitcnt vmcnt(6)" ::: "memory");
    __builtin_amdgcn_s_barrier();
    __builtin_amdgcn_sched_barrier(0);
    __builtin_amdgcn_s_setprio(1);
    G_COMPUTE(kt & 1)
    __builtin_amdgcn_s_setprio(0);
    __builtin_amdgcn_sched_barrier(0);
    __builtin_amdgcn_s_barrier();
  }
  asm volatile("s_waitcnt vmcnt(0)" ::: "memory");
  __builtin_amdgcn_s_barrier();
  G_COMPUTE(1)

  const int rg = (lane >> 4) * 4;
  #pragma unroll
  for (int i = 0; i < AI; ++i) {
    #pragma unroll
    for (int j = 0; j < 4; ++j) {
      const int col = n0 + wc * 64 + j * 16 + fr;
      if constexpr (MODE == 2) {
        const int h = col >> 6, hd = col & 63;
        const int row = m0 + wr * (BMT / 2) + i * 16 + rg;
        const int bq = row >> 11, qq = row & 2047;
        bf16x4 o;
        #pragma unroll
        for (int r = 0; r < 4; ++r) o[r] = (__bf16)(acc[i][j][r] + bias[col]);
        *(bf16x4*)&Vtg[(((size_t)bq * NHEADS + h) * HEADD + hd) * S_LEN + qq] = o;
      } else {
        #pragma unroll
        for (int r = 0; r < 4; ++r) {
          const int row = m0 + wr * (BMT / 2) + i * 16 + rg + r;
          if constexpr (MODE == 0) {
            Ob[(size_t)row * HDIM + col] = (__bf16)(acc[i][j][r] + bias[col] * bscale);
          } else {
            Of[(size_t)row * HDIM + col] =
                acc[i][j][r] + bias[col] + resid[(size_t)row * HDIM + col];
          }
        }
      }
    }
  }
  #undef G_STAGE
  #undef G_COMPUTE
}

__global__ __launch_bounds__(256)
void qkv_kernel(const __bf16* __restrict__ Qc, const __bf16* __restrict__ Kc,
                const __bf16* __restrict__ Vc, const __bf16* __restrict__ Wt,
                const float* __restrict__ bq, const float* __restrict__ bk,
                const float* __restrict__ bv,
                __bf16* __restrict__ Qb, __bf16* __restrict__ Kb,
                __bf16* __restrict__ Vtg)
{
  __shared__ __bf16 smem[2 * 128 * 64 * 2];
  __bf16* As = smem;
  __bf16* Bs = smem + 2 * 128 * 64;
  const int z = blockIdx.z;
  if (z == 2) {
    gemm_body<2, 128>(As, Bs, Vc, Wt + (size_t)2 * HDIM * HDIM, bv, 1.0f,
                      nullptr, nullptr, nullptr, Vtg);
  } else {
    gemm_body<0, 128>(As, Bs, z ? Kc : Qc, Wt + (size_t)z * HDIM * HDIM,
                      z ? bk : bq, z ? 1.0f : K2EXP, nullptr,
                      z ? Kb : Qb, nullptr, nullptr);
  }
}

__global__ __launch_bounds__(256)
void fc_kernel(const __bf16* __restrict__ A, const __bf16* __restrict__ Wt,
               const float* __restrict__ bias, const float* __restrict__ resid,
               float* __restrict__ Of)
{
  __shared__ __bf16 smem[2 * 64 * 64 + 2 * 128 * 64];
  __bf16* As = smem;
  __bf16* Bs = smem + 2 * 64 * 64;
  gemm_body<1, 64>(As, Bs, A, Wt + (size_t)3 * HDIM * HDIM, bias, 1.0f, resid,
                   nullptr, Of, nullptr);
}

// ============================================================= attention ===
// 8 waves (512 thr), 128 q/block; wave (qt,kvh)=(w>>1,w&1): 32q x 32kv-half
// slice per 64-kv tile. Same 512-block grid & staging bytes as r9 (1 gload
// K + 1 gload V per wave per tile), but 16 waves/CU (4/SIMD) and per-wave
// serial chains halved (4 QK + 6 PV MFMA, 16 exp). kv-half partials
// combined at end through retired LDS in two qt-phases (24.5 KB).
// SINGLE barrier per tile; counted vmcnt(3) (=1 mask + 2 gloads of t+1).
// Swapped QK^T: lane owns q = lane&31; kv = (reg&3)+8*(reg>>2)+4*(lane>>5)
// + 32*kvh. Q pre-scaled by log2(e)/32 -> exp2 direct. Mask mbH + sbfe.
// Row-sum via ones-B MFMA in PV accumulator layout.
__global__ __launch_bounds__(512)
void attn_kernel(const __bf16* __restrict__ Qb, const __bf16* __restrict__ Kb,
                 const __bf16* __restrict__ Vtg, const unsigned* __restrict__ mbH,
                 __bf16* __restrict__ AO)
{
  __shared__ __align__(16) char smem[32768];
  __bf16 (*Ks)[64][64] = (__bf16(*)[64][64])smem;            // 16 KB
  __bf16 (*Vt)[64][64] = (__bf16(*)[64][64])(smem + 16384);  // 16 KB

  const int bh = blockIdx.x, b = bh >> 4, h = bh & 15;
  const int tid = threadIdx.x, lane = tid & 63, w = tid >> 6;
  const int fr = lane & 31, hi = lane >> 5;
  const int qt = w >> 1, kvh = w & 1;
  const int qw = blockIdx.y * 128 + qt * 32;
  const int q  = qw + fr;

  // Q B-frags (reused all tiles)
  bf16x8 qf[4];
  #pragma unroll
  for (int st = 0; st < 4; ++st)
    qf[st] = *(const bf16x8*)&Qb[((size_t)b * S_LEN + q) * HDIM + h * HEADD + st * 16 + hi * 8];

  // staging: wave w covers rows [w*8, w*8+8): ONE gload16 per matrix per tile
  const int srl = w * 8 + (lane >> 3);
  const int ssw = ((lane & 7) ^ (srl & 7)) * 8;
  const __bf16* ksrc = Kb  + ((size_t)b * S_LEN + srl) * HDIM + h * HEADD + ssw;
  const __bf16* vsrc = Vtg + ((size_t)bh * HEADD + srl) * S_LEN + ssw;
  const unsigned* tbl = mbH + ((size_t)(hi * 2 + b) * 32) * S_LEN + q;

  bf16x8 ones;
  #pragma unroll
  for (int e = 0; e < 8; ++e) ones[e] = (__bf16)1.0f;

  f32x16 o0 = {}, o1 = {}, l_acc = {};
  unsigned mv, nm = 0;

  // prologue: mask(0) + stage tile 0 -> buf0
  mv = tbl[0];
  gload16(ksrc, (void*)&Ks[0][w * 8][0]);
  gload16(vsrc, (void*)&Vt[0][w * 8][0]);

  for (int t = 0; t < 32; ++t) {
    const int buf = t & 1;
    __builtin_amdgcn_s_barrier();
    if (t < 31) {
      nm = tbl[(size_t)(t + 1) * S_LEN];
      gload16(ksrc + (size_t)(t + 1) * 64 * HDIM, (void*)&Ks[buf ^ 1][w * 8][0]);
      gload16(vsrc + (size_t)(t + 1) * 64,        (void*)&Vt[buf ^ 1][w * 8][0]);
      asm volatile("s_waitcnt vmcnt(3)" ::: "memory");
    } else {
      asm volatile("s_waitcnt vmcnt(0)" ::: "memory");
    }
    __builtin_amdgcn_sched_barrier(0);

    const __bf16* Kbuf = &Ks[buf][0][0];
    const __bf16* Vbuf = &Vt[buf][0][0];

    // ---- S^T = K Q^T (this wave's 32-kv half)
    f32x16 s = {};
    __builtin_amdgcn_s_setprio(1);
    #pragma unroll
    for (int st = 0; st < 4; ++st)
      s = __builtin_amdgcn_mfma_f32_32x32x16_bf16(
          lds_rdS<128>(Kbuf, kvh * 32 + fr, st * 32 + hi * 16), qf[st], s, 0, 0, 0);
    __builtin_amdgcn_s_setprio(0);

    // ---- p = exp2(s) (scale pre-folded), mask via sbfe sign-bit AND
    float pp[16];
    #pragma unroll
    for (int j = 0; j < 16; ++j) {
      const float e = __builtin_amdgcn_exp2f(s[j]);
      const unsigned a = (unsigned)__builtin_amdgcn_sbfe(mv, j + 16 * kvh, 1);
      pp[j] = __uint_as_float(a & __float_as_uint(e));
    }

    // ---- P -> PV A-frags (cvt_pk + permlane32_swap)
    bf16x8 pa[2];
    #pragma unroll
    for (int g = 0; g < 2; ++g) {
      const int o = g * 8;
      unsigned x  = cvtpk_bf16(pp[o + 0], pp[o + 1]);
      unsigned x2 = cvtpk_bf16(pp[o + 2], pp[o + 3]);
      unsigned y  = cvtpk_bf16(pp[o + 4], pp[o + 5]);
      unsigned y2 = cvtpk_bf16(pp[o + 6], pp[o + 7]);
      plswap(x, y);
      plswap(x2, y2);
      union { unsigned u[4]; bf16x8 v; } uu;
      uu.u[0] = x; uu.u[1] = x2; uu.u[2] = y; uu.u[3] = y2;
      pa[g] = uu.v;
    }

    // ---- O += P V ; l += P 1   (kv-half columns of V^T)
    __builtin_amdgcn_s_setprio(1);
    #pragma unroll
    for (int g = 0; g < 2; ++g) {
      const int bcol = kvh * 64 + g * 32 + hi * 16;
      l_acc = __builtin_amdgcn_mfma_f32_32x32x16_bf16(pa[g], ones, l_acc, 0, 0, 0);
      o0 = __builtin_amdgcn_mfma_f32_32x32x16_bf16(
          pa[g], lds_rdS<128>(Vbuf, fr,      bcol), o0, 0, 0, 0);
      o1 = __builtin_amdgcn_mfma_f32_32x32x16_bf16(
          pa[g], lds_rdS<128>(Vbuf, 32 + fr, bcol), o1, 0, 0, 0);
    }
    __builtin_amdgcn_s_setprio(0);

    mv = nm;
  }

  // ---- combine kv-half partials through retired LDS (two qt-phases), store
  float* sh = (float*)smem;
  #pragma unroll
  for (int ph = 0; ph < 2; ++ph) {
    __builtin_amdgcn_s_barrier();
    if ((qt >> 1) == ph && kvh) {
      float* p = sh + ((size_t)(qt & 1) * 64 + lane) * 48;
      #pragma unroll
      for (int j = 0; j < 16; ++j) { p[j] = o0[j]; p[16 + j] = o1[j]; p[32 + j] = l_acc[j]; }
    }
    __builtin_amdgcn_s_barrier();
    if ((qt >> 1) == ph && !kvh) {
      const float* p = sh + ((size_t)(qt & 1) * 64 + lane) * 48;
      #pragma unroll
      for (int g = 0; g < 4; ++g) {
        #pragma unroll
        for (int r = 0; r < 4; ++r) {
          const int j = g * 4 + r;
          const float inv = __builtin_amdgcn_rcpf(l_acc[j] + p[32 + j]);
          const int qq = qw + g * 8 + hi * 4 + r;
          AO[((size_t)b * S_LEN + qq) * HDIM + h * HEADD + fr]      =
              (__bf16)((o0[j] + p[j]) * inv);
          AO[((size_t)b * S_LEN + qq) * HDIM + h * HEADD + 32 + fr] =
              (__bf16)((o1[j] + p[16 + j]) * inv);
        }
      }
    }
  }
}

// ============================================================= layernorm ===
__global__ __launch_bounds__(256)
void ln_kernel(float* __restrict__ y, const float* __restrict__ gamma,
               const float* __restrict__ beta)
{
  __shared__ float red[8];
  const int tid = threadIdx.x;
  float* p = y + (size_t)blockIdx.x * HDIM;

  float4 vv = *(const float4*)&p[tid * 4];
  float s  = vv.x + vv.y + vv.z + vv.w;
  float ss = vv.x * vv.x + vv.y * vv.y + vv.z * vv.z + vv.w * vv.w;
  #pragma unroll
  for (int d = 1; d < 64; d <<= 1) {
    s  += __shfl_xor(s, d);
    ss += __shfl_xor(ss, d);
  }
  const int wid = tid >> 6;
  if ((tid & 63) == 0) { red[wid * 2] = s; red[wid * 2 + 1] = ss; }
  __syncthreads();
  s  = red[0] + red[2] + red[4] + red[6];
  ss = red[1] + red[3] + red[5] + red[7];
  const float mean = s * (1.0f / HDIM);
  const float var  = ss * (1.0f / HDIM) - mean * mean;
  const float inv  = rsqrtf(var + 1e-5f);

  const float4 g  = *(const float4*)&gamma[tid * 4];
  const float4 bt = *(const float4*)&beta[tid * 4];
  vv.x = (vv.x - mean) * inv * g.x + bt.x;
  vv.y = (vv.y - mean) * inv * g.y + bt.y;
  vv.z = (vv.z - mean) * inv * g.z + bt.z;
  vv.w = (vv.w - mean) * inv * g.w + bt.w;
  *(float4*)&p[tid * 4] = vv;
}

// ================================================================ launch ===
extern "C" void kernel_launch(void* const* d_in, const int* in_sizes, int n_in,
                              void* d_out, int out_size, void* d_ws, size_t ws_size,
                              hipStream_t stream) {
  const float* q     = (const float*)d_in[0];
  const float* k     = (const float*)d_in[1];
  const float* v     = (const float*)d_in[2];
  const int*   mask  = (const int*)  d_in[3];
  const float* Wq    = (const float*)d_in[4];
  const float* bq    = (const float*)d_in[5];
  const float* Wk    = (const float*)d_in[6];
  const float* bk    = (const float*)d_in[7];
  const float* Wv    = (const float*)d_in[8];
  const float* bv    = (const float*)d_in[9];
  const float* Wfc   = (const float*)d_in[10];
  const float* bfc   = (const float*)d_in[11];
  const float* gamma = (const float*)d_in[12];
  const float* beta  = (const float*)d_in[13];
  float* out = (float*)d_out;

  char* ws = (char*)d_ws;
  const size_t MB16 = (size_t)MTOT * HDIM * 2;     // 8.39 MB per bf16 matrix
  unsigned* mbH = (unsigned*)ws;                   // 1 MB
  __bf16* Wt  = (__bf16*)(ws + (1u << 20));        // 8 MB
  __bf16* Qc  = (__bf16*)(ws + (1u << 20) + 4 * (size_t)HDIM * HDIM * 2);
  __bf16* Kc  = (__bf16*)((char*)Qc + MB16);
  __bf16* Vc  = (__bf16*)((char*)Kc + MB16);
  __bf16* Qb  = (__bf16*)((char*)Vc + MB16);
  __bf16* Kb  = (__bf16*)((char*)Qb + MB16);
  __bf16* Vtg = (__bf16*)((char*)Kb + MB16);       // V^T written by qkv z=2
  __bf16* AO  = Kc;   // alias: Kc dead after qkv

  const dim3 blk(256);

  prologue_kernel<<<dim3(39936), blk, 0, stream>>>(
      q, k, v, mask, Wq, Wk, Wv, Wfc, Qc, Kc, Vc, mbH, Wt);

  qkv_kernel<<<dim3(HDIM / 128, MTOT / 128, 3), blk, 0, stream>>>(
      Qc, Kc, Vc, Wt, bq, bk, bv, Qb, Kb, Vtg);

  attn_kernel<<<dim3(BATCH * NHEADS, S_LEN / 128), dim3(512), 0, stream>>>(
      Qb, Kb, Vtg, mbH, AO);

  fc_kernel<<<dim3(HDIM / 128, MTOT / 64), blk, 0, stream>>>(
      AO, Wt, bfc, q, out);

  ln_kernel<<<dim3(MTOT), blk, 0, stream>>>(out, gamma, beta);
}